// Round 4
// baseline (196.234 us; speedup 1.0000x reference)
//
#include <hip/hip_runtime.h>

// Biquad DF2T over [B=512, T=48000] fp32, per-channel coeffs.
// Two-dispatch block-parallel scan (breaks the one-block-per-channel
// latency floor measured at ~66 us across three prior structures):
//   K1: 4096 blocks (512 ch x 8 chunks of 6000). Each block computes its
//       chunk's aggregate affine transform (P 2x2, w 2) -> d_ws (6 floats).
//   K2: 4096 blocks. Each block folds the <=7 preceding chunk aggregates
//       (uniform reads) into its entry state, recomputes the local scan,
//       replays with exact reference arithmetic, and writes y coalesced
//       (LDS transpose) with nontemporal stores. x re-read hits L3.
// K1->K2 visibility is guaranteed by dispatch-boundary coherence.
// Per block: 500 active threads, 12 samples/thread in 3 float4 registers.

#define B_CH   512
#define T_LEN  48000
#define CPC    8            // chunks per channel
#define CHUNK  6000         // samples per chunk
#define NBLK   (B_CH * CPC) // 4096
#define NACT   500          // active threads per block
#define L      12           // samples per thread
#define NF4R   3            // float4 per thread row
#define STRIDE 13           // padded LDS row stride (floats)
#define NF4C   1500         // float4 per chunk
#define NWAVE  8

typedef float f4_t __attribute__((ext_vector_type(4)));

// Raw barrier: ds-ops drained (lgkmcnt), vmcnt left in flight.
__device__ __forceinline__ void barrier_lds()
{
    asm volatile("s_waitcnt lgkmcnt(0)" ::: "memory");
    __builtin_amdgcn_s_barrier();
}

// G = A^L, A = [[-a1,1],[-a2,0]] (binary exponentiation; powers commute)
__device__ __forceinline__ void mat_pow(float A1, float A2,
                                        float& G00, float& G01,
                                        float& G10, float& G11)
{
    float m00 = -A1, m01 = 1.f, m10 = -A2, m11 = 0.f;
    float f00 = 1.f, f01 = 0.f, f10 = 0.f, f11 = 1.f;
    int e = L;
    while (e) {
        if (e & 1) {
            const float t00 = f00*m00 + f01*m10, t01 = f00*m01 + f01*m11;
            const float t10 = f10*m00 + f11*m10, t11 = f10*m01 + f11*m11;
            f00 = t00; f01 = t01; f10 = t10; f11 = t11;
        }
        e >>= 1;
        if (!e) break;
        const float s00 = m00*m00 + m01*m10, s01 = m00*m01 + m01*m11;
        const float s10 = m10*m00 + m11*m10, s11 = m10*m01 + m11*m11;
        m00 = s00; m01 = s01; m10 = s10; m11 = s11;
    }
    G00 = f00; G01 = f01; G10 = f10; G11 = f11;
}

// ---------------- K1: per-chunk aggregate ----------------
__global__ __launch_bounds__(512, 4) void k1_agg(
    const float* __restrict__ x,
    const float* __restrict__ b0v, const float* __restrict__ b1v,
    const float* __restrict__ b2v,
    const float* __restrict__ a1v, const float* __restrict__ a2v,
    float* __restrict__ ws)
{
    __shared__ float aggP[NWAVE][4];
    __shared__ float aggW[NWAVE][2];

    const int bid  = blockIdx.x;
    const int b    = bid >> 3;
    const int c    = bid & (CPC - 1);
    const int t    = threadIdx.x;
    const int lane = t & 63;
    const int wid  = t >> 6;

    const float A1 = a1v[b], A2 = a2v[b];
    const float B0 = b0v[b], B1 = b1v[b], B2 = b2v[b];
    const float c1 = B1 - A1 * B0;
    const float c2 = B2 - A2 * B0;

    float G00, G01, G10, G11;
    mat_pow(A1, A2, G00, G01, G10, G11);

    // load own 12-sample row + zero-state response (y-eliminated form)
    float P00, P01, P10, P11, w0, w1;
    if (t < NACT) {
        const f4_t* p = (const f4_t*)(x + (size_t)b * T_LEN + c * CHUNK + t * L);
        const f4_t v0 = p[0], v1 = p[1], v2 = p[2];
        float z1 = 0.f, z2 = 0.f;
        const float xs[L] = { v0.x, v0.y, v0.z, v0.w, v1.x, v1.y, v1.z, v1.w,
                              v2.x, v2.y, v2.z, v2.w };
        #pragma unroll
        for (int i = 0; i < L; ++i) {
            const float xn = xs[i];
            const float n1 = c1 * xn + z2 - A1 * z1;
            z2 = c2 * xn - A2 * z1;
            z1 = n1;
        }
        P00 = G00; P01 = G01; P10 = G10; P11 = G11; w0 = z1; w1 = z2;
    } else {
        P00 = 1.f; P01 = 0.f; P10 = 0.f; P11 = 1.f; w0 = 0.f; w1 = 0.f;
    }

    // intra-wave inclusive Kogge-Stone via shuffles
    #pragma unroll
    for (int off = 1; off < 64; off <<= 1) {
        const float e00 = __shfl_up(P00, off);
        const float e01 = __shfl_up(P01, off);
        const float e10 = __shfl_up(P10, off);
        const float e11 = __shfl_up(P11, off);
        const float u0  = __shfl_up(w0,  off);
        const float u1  = __shfl_up(w1,  off);
        if (lane >= off) {
            const float n00 = P00*e00 + P01*e10, n01 = P00*e01 + P01*e11;
            const float n10 = P10*e00 + P11*e10, n11 = P10*e01 + P11*e11;
            w0 = P00*u0 + P01*u1 + w0;
            w1 = P10*u0 + P11*u1 + w1;
            P00 = n00; P01 = n01; P10 = n10; P11 = n11;
        }
    }

    if (lane == 63) {
        aggP[wid][0] = P00; aggP[wid][1] = P01;
        aggP[wid][2] = P10; aggP[wid][3] = P11;
        aggW[wid][0] = w0;  aggW[wid][1] = w1;
    }
    barrier_lds();

    if (t == 0) {
        // compose wave aggregates in time order: F := E_k . F
        float p00 = 1.f, p01 = 0.f, p10 = 0.f, p11 = 1.f, q0 = 0.f, q1 = 0.f;
        #pragma unroll
        for (int k = 0; k < NWAVE; ++k) {
            const float e00 = aggP[k][0], e01 = aggP[k][1];
            const float e10 = aggP[k][2], e11 = aggP[k][3];
            const float s0  = aggW[k][0], s1  = aggW[k][1];
            const float n00 = e00*p00 + e01*p10, n01 = e00*p01 + e01*p11;
            const float n10 = e10*p00 + e11*p10, n11 = e10*p01 + e11*p11;
            const float nw0 = e00*q0 + e01*q1 + s0;
            const float nw1 = e10*q0 + e11*q1 + s1;
            p00 = n00; p01 = n01; p10 = n10; p11 = n11; q0 = nw0; q1 = nw1;
        }
        float* o = ws + (size_t)bid * 6;
        o[0] = p00; o[1] = p01; o[2] = p10; o[3] = p11; o[4] = q0; o[5] = q1;
    }
}

// ---------------- K2: entry fold + replay + coalesced store ----------------
__global__ __launch_bounds__(512, 4) void k2_solve(
    const float* __restrict__ x,
    const float* __restrict__ b0v, const float* __restrict__ b1v,
    const float* __restrict__ b2v,
    const float* __restrict__ a1v, const float* __restrict__ a2v,
    const float* __restrict__ ws,
    float* __restrict__ y)
{
    __shared__ float xl[NACT * STRIDE];   // 6500 floats = 26 KB (y transpose)
    __shared__ float aggP[NWAVE][4];
    __shared__ float aggW[NWAVE][2];

    const int bid  = blockIdx.x;
    const int b    = bid >> 3;
    const int c    = bid & (CPC - 1);
    const int t    = threadIdx.x;
    const int lane = t & 63;
    const int wid  = t >> 6;

    const float A1 = a1v[b], A2 = a2v[b];
    const float B0 = b0v[b], B1 = b1v[b], B2 = b2v[b];
    const float c1 = B1 - A1 * B0;
    const float c2 = B2 - A2 * B0;

    float G00, G01, G10, G11;
    mat_pow(A1, A2, G00, G01, G10, G11);

    // issue own 12-sample row load early
    f4_t xr[NF4R];
    if (t < NACT) {
        const f4_t* p = (const f4_t*)(x + (size_t)b * T_LEN + c * CHUNK + t * L);
        xr[0] = p[0]; xr[1] = p[1]; xr[2] = p[2];
    }

    // entry state: fold aggregates of preceding chunks (uniform, redundant)
    float cz1 = 0.f, cz2 = 0.f;
    {
        const float* a = ws + (size_t)(b * CPC) * 6;
        for (int k = 0; k < c; ++k) {
            const float n0 = a[6*k+0]*cz1 + a[6*k+1]*cz2 + a[6*k+4];
            const float n1 = a[6*k+2]*cz1 + a[6*k+3]*cz2 + a[6*k+5];
            cz1 = n0; cz2 = n1;
        }
    }

    // local zero-state response (registers only)
    float P00, P01, P10, P11, w0, w1;
    if (t < NACT) {
        float z1 = 0.f, z2 = 0.f;
        #pragma unroll
        for (int k = 0; k < NF4R; ++k) {
            const f4_t v = xr[k];
            { const float xn = v.x; const float n1 = c1*xn + z2 - A1*z1; z2 = c2*xn - A2*z1; z1 = n1; }
            { const float xn = v.y; const float n1 = c1*xn + z2 - A1*z1; z2 = c2*xn - A2*z1; z1 = n1; }
            { const float xn = v.z; const float n1 = c1*xn + z2 - A1*z1; z2 = c2*xn - A2*z1; z1 = n1; }
            { const float xn = v.w; const float n1 = c1*xn + z2 - A1*z1; z2 = c2*xn - A2*z1; z1 = n1; }
        }
        P00 = G00; P01 = G01; P10 = G10; P11 = G11; w0 = z1; w1 = z2;
    } else {
        P00 = 1.f; P01 = 0.f; P10 = 0.f; P11 = 1.f; w0 = 0.f; w1 = 0.f;
    }

    // intra-wave inclusive Kogge-Stone via shuffles
    #pragma unroll
    for (int off = 1; off < 64; off <<= 1) {
        const float e00 = __shfl_up(P00, off);
        const float e01 = __shfl_up(P01, off);
        const float e10 = __shfl_up(P10, off);
        const float e11 = __shfl_up(P11, off);
        const float u0  = __shfl_up(w0,  off);
        const float u1  = __shfl_up(w1,  off);
        if (lane >= off) {
            const float n00 = P00*e00 + P01*e10, n01 = P00*e01 + P01*e11;
            const float n10 = P10*e00 + P11*e10, n11 = P10*e01 + P11*e11;
            w0 = P00*u0 + P01*u1 + w0;
            w1 = P10*u0 + P11*u1 + w1;
            P00 = n00; P01 = n01; P10 = n10; P11 = n11;
        }
    }

    if (lane == 63) {
        aggP[wid][0] = P00; aggP[wid][1] = P01;
        aggP[wid][2] = P10; aggP[wid][3] = P11;
        aggW[wid][0] = w0;  aggW[wid][1] = w1;
    }

    // exclusive-within-wave = inclusive shifted down one lane
    float E00 = __shfl_up(P00, 1), E01 = __shfl_up(P01, 1);
    float E10 = __shfl_up(P10, 1), E11 = __shfl_up(P11, 1);
    float Ew0 = __shfl_up(w0, 1),  Ew1 = __shfl_up(w1, 1);
    if (lane == 0) { E00 = 1.f; E01 = 0.f; E10 = 0.f; E11 = 1.f; Ew0 = 0.f; Ew1 = 0.f; }

    barrier_lds();

    // carry-aware fold of wave aggregates (wave-uniform broadcasts)
    float s0 = cz1, s1 = cz2, my0 = cz1, my1 = cz2;
    #pragma unroll
    for (int k = 0; k < NWAVE; ++k) {
        if (k == wid) { my0 = s0; my1 = s1; }
        const float p0 = aggP[k][0], p1 = aggP[k][1];
        const float p2 = aggP[k][2], p3 = aggP[k][3];
        const float q0 = aggW[k][0], q1 = aggW[k][1];
        const float n0 = p0*s0 + p1*s1 + q0;
        const float n1 = p2*s0 + p3*s1 + q1;
        s0 = n0; s1 = n1;
    }

    // this thread's true initial state
    float z1 = E00*my0 + E01*my1 + Ew0;
    float z2 = E10*my0 + E11*my1 + Ew1;

    // replay with exact reference arithmetic: registers -> LDS rows
    if (t < NACT) {
        float* r = &xl[t * STRIDE];
        #pragma unroll
        for (int k = 0; k < NF4R; ++k) {
            const f4_t v = xr[k];
            { const float xn = v.x; const float yn = B0*xn + z1; r[4*k+0] = yn;
              const float n1 = B1*xn - A1*yn + z2; z2 = B2*xn - A2*yn; z1 = n1; }
            { const float xn = v.y; const float yn = B0*xn + z1; r[4*k+1] = yn;
              const float n1 = B1*xn - A1*yn + z2; z2 = B2*xn - A2*yn; z1 = n1; }
            { const float xn = v.z; const float yn = B0*xn + z1; r[4*k+2] = yn;
              const float n1 = B1*xn - A1*yn + z2; z2 = B2*xn - A2*yn; z1 = n1; }
            { const float xn = v.w; const float yn = B0*xn + z1; r[4*k+3] = yn;
              const float n1 = B1*xn - A1*yn + z2; z2 = B2*xn - A2*yn; z1 = n1; }
        }
    }
    barrier_lds();

    // writeback: LDS rows -> nontemporal coalesced float4 stores
    float* ys = y + (size_t)b * T_LEN + c * CHUNK;
    #pragma unroll
    for (int k = 0; k < NF4R; ++k) {
        const int g = t + 512 * k;
        if (g < NF4C) {
            const int own = g / 3;
            const int off = (g - 3 * own) * 4;
            const float* sp = &xl[own * STRIDE + off];
            f4_t v;
            v.x = sp[0]; v.y = sp[1]; v.z = sp[2]; v.w = sp[3];
            __builtin_nontemporal_store(v, (f4_t*)(ys + 4 * g));
        }
    }
}

extern "C" void kernel_launch(void* const* d_in, const int* in_sizes, int n_in,
                              void* d_out, int out_size, void* d_ws, size_t ws_size,
                              hipStream_t stream) {
    const float* x  = (const float*)d_in[0];
    const float* b0 = (const float*)d_in[1];
    const float* b1 = (const float*)d_in[2];
    const float* b2 = (const float*)d_in[3];
    const float* a1 = (const float*)d_in[4];
    const float* a2 = (const float*)d_in[5];
    float* y  = (float*)d_out;
    float* ws = (float*)d_ws;   // 4096 * 6 floats = 96 KB

    k1_agg  <<<dim3(NBLK), dim3(512), 0, stream>>>(x, b0, b1, b2, a1, a2, ws);
    k2_solve<<<dim3(NBLK), dim3(512), 0, stream>>>(x, b0, b1, b2, a1, a2, ws, y);
}